// Round 21
// baseline (753.733 us; speedup 1.0000x reference)
//
#include <hip/hip_runtime.h>

typedef unsigned short u16;
using bf16x8 = __attribute__((ext_vector_type(8))) __bf16;
using f32x4  = __attribute__((ext_vector_type(4))) float;
using u16x8  = __attribute__((ext_vector_type(8))) u16;

__device__ __forceinline__ u16 f2bf(float f) {
    unsigned u = __builtin_bit_cast(unsigned, f);
    u += 0x7FFFu + ((u >> 16) & 1u);           // round-to-nearest-even
    return (u16)(u >> 16);
}
__device__ __forceinline__ float bf2f(u16 h) {
    unsigned u = ((unsigned)h) << 16;
    return __builtin_bit_cast(float, u);
}
__device__ __forceinline__ u16 to_bf(float f) { return f2bf(f); }
__device__ __forceinline__ u16 to_bf(u16 h)   { return h; }

// async global->LDS, 16B per lane; LDS base must be wave-uniform.
__device__ __forceinline__ void gload_lds16(const u16* g, u16* l) {
    __builtin_amdgcn_global_load_lds(
        (const __attribute__((address_space(1))) unsigned int*)g,
        (__attribute__((address_space(3))) unsigned int*)l,
        16, 0, 0);
}

// ---------------- fp32 -> bf16 elementwise (vectorized) ----------------
__global__ __launch_bounds__(256) void k_cvt_f32_bf16(const float* __restrict__ in,
                                                      u16* __restrict__ out, long n) {
    long i = ((long)blockIdx.x * 256 + threadIdx.x) * 8;
    if (i + 8 > n) return;
    f32x4 a = *(const f32x4*)(in + i);
    f32x4 b = *(const f32x4*)(in + i + 4);
    u16x8 o;
    o[0] = f2bf(a[0]); o[1] = f2bf(a[1]); o[2] = f2bf(a[2]); o[3] = f2bf(a[3]);
    o[4] = f2bf(b[0]); o[5] = f2bf(b[1]); o[6] = f2bf(b[2]); o[7] = f2bf(b[3]);
    __builtin_nontemporal_store(o, (u16x8*)(out + i));
}

// ---------------- tiled transpose (f32->bf16) for weights ----------------
template <typename T>
__global__ __launch_bounds__(256) void k_transpose_bf16(
    const T* __restrict__ in, long in_rs, long in_bs,
    u16* __restrict__ out, long out_rs, long out_bs, int R, int C) {
    __shared__ u16 tile[32][33];
    const int b = blockIdx.z;
    const T* ip = in + (long)b * in_bs;
    u16* op = out + (long)b * out_bs;
    const int tx = threadIdx.x, ty = threadIdx.y;
    const long r0 = (long)blockIdx.y * 32, c0 = (long)blockIdx.x * 32;
#pragma unroll
    for (int i = 0; i < 4; ++i) {
        int r = ty + i * 8;
        tile[r][tx] = to_bf(ip[(r0 + r) * in_rs + c0 + tx]);
    }
    __syncthreads();
#pragma unroll
    for (int i = 0; i < 4; ++i) {
        int c = ty + i * 8;
        op[(c0 + c) * out_rs + r0 + tx] = tile[tx][c];
    }
}

// --------- reduce per-block partial row sums -> reciprocal ----------
// psum: [Z][nx][4096] (written by QK^T blocks), rrow: [Z*4096]
__global__ __launch_bounds__(256) void k_psum_recip(const float* __restrict__ psum,
                                                    float* __restrict__ rrow,
                                                    int nx, long total) {
    long idx = (long)blockIdx.x * 256 + threadIdx.x;
    if (idx >= total) return;
    const long z = idx >> 12, row = idx & 4095;
    const float* p = psum + (z * nx) * 4096 + row;
    float s = 0.f;
    for (int x = 0; x < nx; ++x) s += p[(long)x * 4096];
    rrow[idx] = 1.0f / s;
}

// ====== 128x256 bf16 GEMM, BK=32, 3-buffer ring, 2 blocks/CU, C = A*B^T ======
// Round-20 proven structure (604.6 us) + NON-TEMPORAL epilogue stores (all
// GEMM outputs are streaming, never L2-hot when read -> keep operand panels
// resident) + rrow-commute (PV writes unnormalized O via EPI 0; ff applies
// rrow[row]*acc + bias, exactly equivalent).
// EPI 0: bf16(acc)  1: bf16(exp(acc*scale)) + fused row-sum partials
// EPI 3: f32(rrow[row]*acc + bias[col])
// EPI 4 (kqv): bx<8 -> bf16(acc); bx>=8 -> tile TRANSPOSED to vT via dead
//   staging LDS retile ([256 col][136-pad row]); bit-identical vT values.

#define VMC(n) asm volatile("s_waitcnt vmcnt(" #n ")" ::: "memory")
#define SCHB   __builtin_amdgcn_sched_barrier(0)
#define BAR    __builtin_amdgcn_s_barrier()
#define PRIO1  __builtin_amdgcn_s_setprio(1)
#define PRIO0  __builtin_amdgcn_s_setprio(0)
#define SWZ(b) ((b) ^ ((((b) >> 9) & 1) << 5))

template <int EPI>
__global__ __launch_bounds__(512, 4) void k_gemm3b(
    const u16* __restrict__ Ag, long lda, long sA,
    const u16* __restrict__ Bg, long ldb, long sB,
    void* __restrict__ Cv, long ldc, long sC,
    int K, float scale, const float* __restrict__ rrowZ, long sR,
    const float* __restrict__ bias, float* __restrict__ psum, int nx,
    u16* __restrict__ vTp) {
    __shared__ __align__(16) u16 LDSbuf[3 * 128 * 32 + 3 * 256 * 32];
    u16 (*As)[128 * 32] = (u16(*)[128 * 32])LDSbuf;
    u16 (*Bs)[256 * 32] = (u16(*)[256 * 32])(LDSbuf + 3 * 128 * 32);

    const int tid = threadIdx.x;
    const int lane = tid & 63, wid = tid >> 6;
    const int wm = wid >> 2, wn = wid & 3;   // 2(M) x 4(N) wave grid
    const int z = blockIdx.z;
    // XCD-chunked bijective swizzle (nwg % 8 == 0 for all our launches)
    const int nwg = gridDim.x;
    const int bid = blockIdx.x;
    const int swzb = (bid & 7) * (nwg >> 3) + (bid >> 3);
    const int bx = swzb % nx, by = swzb / nx;
    const long m0 = (long)by * 128;
    const long n0 = (long)bx * 256;
    const u16* A = Ag + (long)z * sA;
    const u16* B = Bg + (long)z * sB;

    // staging sources (linear LDS dest; pre-swizzled global src).
    long aSrc, bSrc0, bSrc1;
    {
        int dg = SWZ(tid * 16);
        aSrc = (m0 + (dg >> 6)) * lda + ((dg & 63) >> 1);
        bSrc0 = (n0 + (dg >> 6)) * ldb + ((dg & 63) >> 1);
        dg = SWZ(8192 + tid * 16);
        bSrc1 = (n0 + (dg >> 6)) * ldb + ((dg & 63) >> 1);
    }
    const int r16 = lane & 15, g = lane >> 4;
    const int vA = SWZ((wm * 64 + r16) * 64 + g * 16);   // byte off in A buf
    const int vB = SWZ((wn * 64 + r16) * 64 + g * 16);   // byte off in B buf

#define STG(bb, kt) do { \
        gload_lds16(A + aSrc + (kt), &As[bb][wid * 512]); \
        gload_lds16(B + bSrc0 + (kt), &Bs[bb][wid * 512]); \
        gload_lds16(B + bSrc1 + (kt), &Bs[bb][4096 + wid * 512]); } while (0)
#define LD4_A(bb) do { _Pragma("unroll") for (int _i = 0; _i < 4; ++_i) \
        afr[_i] = *(const bf16x8*)((const char*)&As[bb][0] + vA + _i * 1024); } while (0)
#define LD4_B(bb) do { _Pragma("unroll") for (int _i = 0; _i < 4; ++_i) \
        bfr[_i] = *(const bf16x8*)((const char*)&Bs[bb][0] + vB + _i * 1024); } while (0)
#define MM16() do { \
        _Pragma("unroll") for (int mf = 0; mf < 4; ++mf) \
        _Pragma("unroll") for (int nf = 0; nf < 4; ++nf) \
            acc[mf][nf] = __builtin_amdgcn_mfma_f32_16x16x32_bf16( \
                afr[mf], bfr[nf], acc[mf][nf], 0, 0, 0); } while (0)

    f32x4 acc[4][4] = {};
    bf16x8 afr[4], bfr[4];

    const int NT = K >> 5;   // K-tiles of 32; NT >= 3 assumed
    // prologue: stage tiles 0 and 1
    STG(0, 0); STG(1, 32);
    VMC(3); SCHB;            // tile 0's 3 loads landed (own); BAR -> collective
    BAR; SCHB;

    int b0 = 0, b1 = 1, b2 = 2;
    for (int t = 0; t < NT; ++t) {
        LD4_A(b0); LD4_B(b0);                       // 8 ds_read_b128
        if (t + 2 < NT) STG(b2, (long)(t + 2) * 32);
        PRIO1; MM16(); PRIO0;                       // compiler-counted lgkmcnt
        if (t + 2 < NT) { VMC(3); }                 // retire tile t+1's loads
        else if (t + 1 < NT) { VMC(0); }            // tail drain
        BAR; SCHB;
        int tm = b0; b0 = b1; b1 = b2; b2 = tm;
    }

    // epilogue. C/D layout: col = lane&15, row = (lane>>4)*4 + j
    const int r_in = (lane >> 4) * 4;
    const int c_in = lane & 15;

    if constexpr (EPI == 4) {
        if (bx >= 8) {
            // transposed V write: acc -> LDS [256 col][136-pad row] -> vT
            u16* t = LDSbuf;
#pragma unroll
            for (int mf = 0; mf < 4; ++mf) {
#pragma unroll
                for (int nf = 0; nf < 4; ++nf) {
                    const int c = wn * 64 + nf * 16 + c_in;
                    const int r = wm * 64 + mf * 16 + r_in;
                    ushort4 pk;
                    pk.x = f2bf(acc[mf][nf][0]); pk.y = f2bf(acc[mf][nf][1]);
                    pk.z = f2bf(acc[mf][nf][2]); pk.w = f2bf(acc[mf][nf][3]);
                    *(ushort4*)(t + c * 136 + r) = pk;
                }
            }
            __syncthreads();
            const int cc = tid >> 1, hf = tid & 1;
            const long zz = m0 >> 12;              // batch of this row panel
            u16* dst = vTp + zz * (1024L * 4096) +
                       (n0 - 2048 + cc) * 4096L + (m0 & 4095) + hf * 64;
            const u16* src = t + cc * 136 + hf * 64;
#pragma unroll
            for (int i = 0; i < 8; ++i)
                __builtin_nontemporal_store(*(const u16x8*)(src + i * 8),
                                            (u16x8*)(dst + i * 8));
            return;
        }
        // bx < 8: fall through to normal bf16 C write below
    }

    float rsum[4][4];
    if constexpr (EPI == 1) {
#pragma unroll
        for (int a = 0; a < 4; ++a)
#pragma unroll
            for (int b = 0; b < 4; ++b) rsum[a][b] = 0.f;
    }
#pragma unroll
    for (int mf = 0; mf < 4; ++mf) {
#pragma unroll
        for (int nf = 0; nf < 4; ++nf) {
            const long cg = n0 + wn * 64 + nf * 16 + c_in;
#pragma unroll
            for (int j = 0; j < 4; ++j) {
                const long rg = m0 + wm * 64 + mf * 16 + r_in + j;
                float v = acc[mf][nf][j];
                if constexpr (EPI == 0 || EPI == 4) {
                    __builtin_nontemporal_store(
                        f2bf(v), (u16*)Cv + (long)z * sC + rg * ldc + cg);
                } else if constexpr (EPI == 1) {
                    float e = __expf(v * scale);
                    __builtin_nontemporal_store(
                        f2bf(e), (u16*)Cv + (long)z * sC + rg * ldc + cg);
                    rsum[mf][j] += e;
                } else {  // EPI == 3: out = rrow[row]*acc + bias[col]
                    __builtin_nontemporal_store(
                        rrowZ[rg] * v + bias[cg],
                        (float*)Cv + (long)z * sC + rg * ldc + cg);
                }
            }
        }
    }
    if constexpr (EPI == 1) {
        // per-block partial row sums -> psum[(z*nx + bx)*M + m0 + row]
        float* ps = (float*)LDSbuf;      // [128][4] scratch (staging LDS dead)
#pragma unroll
        for (int mf = 0; mf < 4; ++mf) {
#pragma unroll
            for (int j = 0; j < 4; ++j) {
                float s = rsum[mf][j];
#pragma unroll
                for (int w = 1; w < 16; w <<= 1) s += __shfl_xor(s, w);
                if ((lane & 15) == 0)
                    ps[(wm * 64 + mf * 16 + (lane >> 4) * 4 + j) * 4 + wn] = s;
            }
        }
        __syncthreads();
        if (tid < 128) {
            float s = ps[tid * 4] + ps[tid * 4 + 1] + ps[tid * 4 + 2] + ps[tid * 4 + 3];
            const long M = (long)(nwg / nx) * 128;
            psum[((long)z * nx + bx) * M + m0 + tid] = s;
        }
    }
#undef MM16
#undef LD4_A
#undef LD4_B
#undef STG
}

extern "C" void kernel_launch(void* const* d_in, const int* in_sizes, int n_in,
                              void* d_out, int out_size, void* d_ws, size_t ws_size,
                              hipStream_t stream) {
    (void)in_sizes; (void)n_in; (void)out_size;
    const int S = 4096;
    const long BS = 4L * S;  // 16384 tokens
    const float* x_f    = (const float*)d_in[0];  // [BS][2048]
    const float* Wqkv_f = (const float*)d_in[1];  // [2048][3072]
    const float* Wff_f  = (const float*)d_in[2];  // [1024][1024]
    const float* bff    = (const float*)d_in[3];  // [1024]
    float* out = (float*)d_out;                   // [BS][1024]

    // batched attention (z=4) needs 4x probs; fall back if ws too small
    const size_t need4 = 67108864UL + 12582912UL + 2097152UL + 100663296UL +
                         33554432UL + 4UL * 33554432UL + 33554432UL + 65536UL +
                         4UL * 16 * 4096 * 4;
    const bool batched = ws_size >= need4;
    const int Z = batched ? 4 : 1;

    char* p = (char*)d_ws;
    u16* x_bf  = (u16*)p; p += BS * 2048 * 2;
    u16* WqkvT = (u16*)p; p += 3072L * 2048 * 2;
    u16* WffT  = (u16*)p; p += 1024L * 1024 * 2;
    u16* kqv   = (u16*)p; p += BS * 3072 * 2;
    u16* vT    = (u16*)p; p += 4L * 1024 * 4096 * 2;
    u16* probs = (u16*)p; p += (long)Z * 4096L * 4096 * 2;
    u16* attn  = (u16*)p; p += BS * 1024 * 2;
    float* rrow = (float*)p; p += 4L * 4096 * 4;   // always full [4][4096]
    float* psum = (float*)p; p += (long)Z * 16 * 4096 * 4;

    // 1. conversions / weight transposes
    k_cvt_f32_bf16<<<dim3((unsigned)(BS * 2048 / 2048)), 256, 0, stream>>>(x_f, x_bf, BS * 2048);
    k_transpose_bf16<float><<<dim3(3072 / 32, 2048 / 32, 1), dim3(32, 8), 0, stream>>>(
        Wqkv_f, 3072, 0, WqkvT, 2048, 0, 2048, 3072);
    k_transpose_bf16<float><<<dim3(1024 / 32, 1024 / 32, 1), dim3(32, 8), 0, stream>>>(
        Wff_f, 1024, 0, WffT, 1024, 0, 1024, 1024);

    // 2. kqv = X @ W_qkv [16384 x 3072], K=2048 (nwg = 12*128 = 1536)
    //    V-columns (bx>=8) are written TRANSPOSED directly to vT (EPI 4).
    k_gemm3b<4><<<dim3(12 * 128, 1, 1), 512, 0, stream>>>(
        x_bf, 2048, 0, WqkvT, 2048, 0, kqv, 3072, 0, 2048, 0.f, nullptr, 0,
        nullptr, nullptr, 12, vT);

    // 3. attention: probs = exp(Q K^T * scale) with fused row-sum partials;
    //    O_unnorm = probs @ V (normalization deferred to the ff epilogue)
    const float scale = 0.08838834764831845f;  // 1/sqrt(128)
    for (int b = 0; b < 4; b += Z) {
        const u16* kbase = kqv + (long)b * S * 3072;  // k at +0, q at +1024
        k_gemm3b<1><<<dim3(16 * 32, 1, Z), 512, 0, stream>>>(
            kbase + 1024, 3072, (long)S * 3072, kbase, 3072, (long)S * 3072,
            probs, 4096, (long)S * S, 1024, scale, nullptr, 0, nullptr, psum, 16,
            nullptr);
        k_psum_recip<<<(Z * 4096 + 255) / 256, 256, 0, stream>>>(
            psum, rrow + (long)b * 4096, 16, (long)Z * 4096);
        k_gemm3b<0><<<dim3(4 * 32, 1, Z), 512, 0, stream>>>(
            probs, 4096, (long)S * S, vT + (long)b * 1024 * 4096, 4096, 1024L * 4096,
            attn + (long)b * S * 1024, 1024, (long)S * 1024,
            4096, 0.f, nullptr, 0, nullptr, nullptr, 4, nullptr);
    }

    // 4. out = rrow[row] * (attn_unnorm @ W_ff) + b_ff  (fp32, nwg = 512)
    k_gemm3b<3><<<dim3(4 * 128, 1, 1), 512, 0, stream>>>(
        attn, 1024, 0, WffT, 1024, 0, out, 1024, 0, 1024, 0.f, rrow, 0,
        bff, nullptr, 4, nullptr);
}

// Round 22
// 603.174 us; speedup vs baseline: 1.2496x; 1.2496x over previous
//
#include <hip/hip_runtime.h>

typedef unsigned short u16;
using bf16x8 = __attribute__((ext_vector_type(8))) __bf16;
using f32x4  = __attribute__((ext_vector_type(4))) float;
using u16x8  = __attribute__((ext_vector_type(8))) u16;

__device__ __forceinline__ u16 f2bf(float f) {
    unsigned u = __builtin_bit_cast(unsigned, f);
    u += 0x7FFFu + ((u >> 16) & 1u);           // round-to-nearest-even
    return (u16)(u >> 16);
}
__device__ __forceinline__ float bf2f(u16 h) {
    unsigned u = ((unsigned)h) << 16;
    return __builtin_bit_cast(float, u);
}
__device__ __forceinline__ u16 to_bf(float f) { return f2bf(f); }
__device__ __forceinline__ u16 to_bf(u16 h)   { return h; }

// async global->LDS, 16B per lane; LDS base must be wave-uniform.
__device__ __forceinline__ void gload_lds16(const u16* g, u16* l) {
    __builtin_amdgcn_global_load_lds(
        (const __attribute__((address_space(1))) unsigned int*)g,
        (__attribute__((address_space(3))) unsigned int*)l,
        16, 0, 0);
}

// ---------------- fp32 -> bf16 elementwise (vectorized) ----------------
__global__ __launch_bounds__(256) void k_cvt_f32_bf16(const float* __restrict__ in,
                                                      u16* __restrict__ out, long n) {
    long i = ((long)blockIdx.x * 256 + threadIdx.x) * 8;
    if (i + 8 > n) return;
    f32x4 a = *(const f32x4*)(in + i);
    f32x4 b = *(const f32x4*)(in + i + 4);
    u16x8 o;
    o[0] = f2bf(a[0]); o[1] = f2bf(a[1]); o[2] = f2bf(a[2]); o[3] = f2bf(a[3]);
    o[4] = f2bf(b[0]); o[5] = f2bf(b[1]); o[6] = f2bf(b[2]); o[7] = f2bf(b[3]);
    *(u16x8*)(out + i) = o;
}

// ---------------- tiled transpose (f32->bf16) for weights ----------------
template <typename T>
__global__ __launch_bounds__(256) void k_transpose_bf16(
    const T* __restrict__ in, long in_rs, long in_bs,
    u16* __restrict__ out, long out_rs, long out_bs, int R, int C) {
    __shared__ u16 tile[32][33];
    const int b = blockIdx.z;
    const T* ip = in + (long)b * in_bs;
    u16* op = out + (long)b * out_bs;
    const int tx = threadIdx.x, ty = threadIdx.y;
    const long r0 = (long)blockIdx.y * 32, c0 = (long)blockIdx.x * 32;
#pragma unroll
    for (int i = 0; i < 4; ++i) {
        int r = ty + i * 8;
        tile[r][tx] = to_bf(ip[(r0 + r) * in_rs + c0 + tx]);
    }
    __syncthreads();
#pragma unroll
    for (int i = 0; i < 4; ++i) {
        int c = ty + i * 8;
        op[(c0 + c) * out_rs + r0 + tx] = tile[tx][c];
    }
}

// --------- reduce per-block partial row sums -> reciprocal ----------
// psum: [Z][nx][4096] (written by QK^T blocks), rrow: [Z*4096]
__global__ __launch_bounds__(256) void k_psum_recip(const float* __restrict__ psum,
                                                    float* __restrict__ rrow,
                                                    int nx, long total) {
    long idx = (long)blockIdx.x * 256 + threadIdx.x;
    if (idx >= total) return;
    const long z = idx >> 12, row = idx & 4095;
    const float* p = psum + (z * nx) * 4096 + row;
    float s = 0.f;
    for (int x = 0; x < nx; ++x) s += p[(long)x * 4096];
    rrow[idx] = 1.0f / s;
}

// ====== 128x256 bf16 GEMM, BK=32, 3-buffer ring, 2 blocks/CU, C = A*B^T ======
// Round-20 proven structure (604.6 us): T1 XCD-chunked block swizzle, 8 waves
// (2M x 4N), per-wave 64x64, LDS swizzle byte ^= ((byte>>9)&1)<<5 both sides,
// per tile: 8 ds_read_b128 + stage t+2 + 16 MFMA -> VMC(3) -> barrier.
// PLAIN stores everywhere (r21 lesson: scalar non-temporal stores defeat L2
// write-combining -> ~2.7x write amplification; nt is only safe at >=line
// granularity). rrow-commute kept: PV writes unnormalized O (EPI 0); the ff
// epilogue applies rrow[row]*acc + bias (exactly equivalent).
// EPI 0: bf16(acc)  1: bf16(exp(acc*scale)) + fused row-sum partials
// EPI 3: f32(rrow[row]*acc + bias[col])
// EPI 4 (kqv): bx<8 -> bf16(acc); bx>=8 -> tile TRANSPOSED to vT via dead
//   staging LDS retile ([256 col][136-pad row]); bit-identical vT values.

#define VMC(n) asm volatile("s_waitcnt vmcnt(" #n ")" ::: "memory")
#define SCHB   __builtin_amdgcn_sched_barrier(0)
#define BAR    __builtin_amdgcn_s_barrier()
#define PRIO1  __builtin_amdgcn_s_setprio(1)
#define PRIO0  __builtin_amdgcn_s_setprio(0)
#define SWZ(b) ((b) ^ ((((b) >> 9) & 1) << 5))

template <int EPI>
__global__ __launch_bounds__(512, 4) void k_gemm3b(
    const u16* __restrict__ Ag, long lda, long sA,
    const u16* __restrict__ Bg, long ldb, long sB,
    void* __restrict__ Cv, long ldc, long sC,
    int K, float scale, const float* __restrict__ rrowZ, long sR,
    const float* __restrict__ bias, float* __restrict__ psum, int nx,
    u16* __restrict__ vTp) {
    __shared__ __align__(16) u16 LDSbuf[3 * 128 * 32 + 3 * 256 * 32];
    u16 (*As)[128 * 32] = (u16(*)[128 * 32])LDSbuf;
    u16 (*Bs)[256 * 32] = (u16(*)[256 * 32])(LDSbuf + 3 * 128 * 32);

    const int tid = threadIdx.x;
    const int lane = tid & 63, wid = tid >> 6;
    const int wm = wid >> 2, wn = wid & 3;   // 2(M) x 4(N) wave grid
    const int z = blockIdx.z;
    // XCD-chunked bijective swizzle (nwg % 8 == 0 for all our launches)
    const int nwg = gridDim.x;
    const int bid = blockIdx.x;
    const int swzb = (bid & 7) * (nwg >> 3) + (bid >> 3);
    const int bx = swzb % nx, by = swzb / nx;
    const long m0 = (long)by * 128;
    const long n0 = (long)bx * 256;
    const u16* A = Ag + (long)z * sA;
    const u16* B = Bg + (long)z * sB;

    // staging sources (linear LDS dest; pre-swizzled global src).
    long aSrc, bSrc0, bSrc1;
    {
        int dg = SWZ(tid * 16);
        aSrc = (m0 + (dg >> 6)) * lda + ((dg & 63) >> 1);
        bSrc0 = (n0 + (dg >> 6)) * ldb + ((dg & 63) >> 1);
        dg = SWZ(8192 + tid * 16);
        bSrc1 = (n0 + (dg >> 6)) * ldb + ((dg & 63) >> 1);
    }
    const int r16 = lane & 15, g = lane >> 4;
    const int vA = SWZ((wm * 64 + r16) * 64 + g * 16);   // byte off in A buf
    const int vB = SWZ((wn * 64 + r16) * 64 + g * 16);   // byte off in B buf

#define STG(bb, kt) do { \
        gload_lds16(A + aSrc + (kt), &As[bb][wid * 512]); \
        gload_lds16(B + bSrc0 + (kt), &Bs[bb][wid * 512]); \
        gload_lds16(B + bSrc1 + (kt), &Bs[bb][4096 + wid * 512]); } while (0)
#define LD4_A(bb) do { _Pragma("unroll") for (int _i = 0; _i < 4; ++_i) \
        afr[_i] = *(const bf16x8*)((const char*)&As[bb][0] + vA + _i * 1024); } while (0)
#define LD4_B(bb) do { _Pragma("unroll") for (int _i = 0; _i < 4; ++_i) \
        bfr[_i] = *(const bf16x8*)((const char*)&Bs[bb][0] + vB + _i * 1024); } while (0)
#define MM16() do { \
        _Pragma("unroll") for (int mf = 0; mf < 4; ++mf) \
        _Pragma("unroll") for (int nf = 0; nf < 4; ++nf) \
            acc[mf][nf] = __builtin_amdgcn_mfma_f32_16x16x32_bf16( \
                afr[mf], bfr[nf], acc[mf][nf], 0, 0, 0); } while (0)

    f32x4 acc[4][4] = {};
    bf16x8 afr[4], bfr[4];

    const int NT = K >> 5;   // K-tiles of 32; NT >= 3 assumed
    // prologue: stage tiles 0 and 1
    STG(0, 0); STG(1, 32);
    VMC(3); SCHB;            // tile 0's 3 loads landed (own); BAR -> collective
    BAR; SCHB;

    int b0 = 0, b1 = 1, b2 = 2;
    for (int t = 0; t < NT; ++t) {
        LD4_A(b0); LD4_B(b0);                       // 8 ds_read_b128
        if (t + 2 < NT) STG(b2, (long)(t + 2) * 32);
        PRIO1; MM16(); PRIO0;                       // compiler-counted lgkmcnt
        if (t + 2 < NT) { VMC(3); }                 // retire tile t+1's loads
        else if (t + 1 < NT) { VMC(0); }            // tail drain
        BAR; SCHB;
        int tm = b0; b0 = b1; b1 = b2; b2 = tm;
    }

    // epilogue. C/D layout: col = lane&15, row = (lane>>4)*4 + j
    const int r_in = (lane >> 4) * 4;
    const int c_in = lane & 15;

    if constexpr (EPI == 4) {
        if (bx >= 8) {
            // transposed V write: acc -> LDS [256 col][136-pad row] -> vT
            u16* t = LDSbuf;
#pragma unroll
            for (int mf = 0; mf < 4; ++mf) {
#pragma unroll
                for (int nf = 0; nf < 4; ++nf) {
                    const int c = wn * 64 + nf * 16 + c_in;
                    const int r = wm * 64 + mf * 16 + r_in;
                    ushort4 pk;
                    pk.x = f2bf(acc[mf][nf][0]); pk.y = f2bf(acc[mf][nf][1]);
                    pk.z = f2bf(acc[mf][nf][2]); pk.w = f2bf(acc[mf][nf][3]);
                    *(ushort4*)(t + c * 136 + r) = pk;
                }
            }
            __syncthreads();
            const int cc = tid >> 1, hf = tid & 1;
            const long zz = m0 >> 12;              // batch of this row panel
            u16* dst = vTp + zz * (1024L * 4096) +
                       (n0 - 2048 + cc) * 4096L + (m0 & 4095) + hf * 64;
            const u16* src = t + cc * 136 + hf * 64;
#pragma unroll
            for (int i = 0; i < 8; ++i)
                *(u16x8*)(dst + i * 8) = *(const u16x8*)(src + i * 8);
            return;
        }
        // bx < 8: fall through to normal bf16 C write below
    }

    float rsum[4][4];
    if constexpr (EPI == 1) {
#pragma unroll
        for (int a = 0; a < 4; ++a)
#pragma unroll
            for (int b = 0; b < 4; ++b) rsum[a][b] = 0.f;
    }
#pragma unroll
    for (int mf = 0; mf < 4; ++mf) {
#pragma unroll
        for (int nf = 0; nf < 4; ++nf) {
            const long cg = n0 + wn * 64 + nf * 16 + c_in;
#pragma unroll
            for (int j = 0; j < 4; ++j) {
                const long rg = m0 + wm * 64 + mf * 16 + r_in + j;
                float v = acc[mf][nf][j];
                if constexpr (EPI == 0 || EPI == 4) {
                    ((u16*)Cv)[(long)z * sC + rg * ldc + cg] = f2bf(v);
                } else if constexpr (EPI == 1) {
                    float e = __expf(v * scale);
                    ((u16*)Cv)[(long)z * sC + rg * ldc + cg] = f2bf(e);
                    rsum[mf][j] += e;
                } else {  // EPI == 3: out = rrow[row]*acc + bias[col]
                    ((float*)Cv)[(long)z * sC + rg * ldc + cg] =
                        rrowZ[rg] * v + bias[cg];
                }
            }
        }
    }
    if constexpr (EPI == 1) {
        // per-block partial row sums -> psum[(z*nx + bx)*M + m0 + row]
        float* ps = (float*)LDSbuf;      // [128][4] scratch (staging LDS dead)
#pragma unroll
        for (int mf = 0; mf < 4; ++mf) {
#pragma unroll
            for (int j = 0; j < 4; ++j) {
                float s = rsum[mf][j];
#pragma unroll
                for (int w = 1; w < 16; w <<= 1) s += __shfl_xor(s, w);
                if ((lane & 15) == 0)
                    ps[(wm * 64 + mf * 16 + (lane >> 4) * 4 + j) * 4 + wn] = s;
            }
        }
        __syncthreads();
        if (tid < 128) {
            float s = ps[tid * 4] + ps[tid * 4 + 1] + ps[tid * 4 + 2] + ps[tid * 4 + 3];
            const long M = (long)(nwg / nx) * 128;
            psum[((long)z * nx + bx) * M + m0 + tid] = s;
        }
    }
#undef MM16
#undef LD4_A
#undef LD4_B
#undef STG
}

extern "C" void kernel_launch(void* const* d_in, const int* in_sizes, int n_in,
                              void* d_out, int out_size, void* d_ws, size_t ws_size,
                              hipStream_t stream) {
    (void)in_sizes; (void)n_in; (void)out_size;
    const int S = 4096;
    const long BS = 4L * S;  // 16384 tokens
    const float* x_f    = (const float*)d_in[0];  // [BS][2048]
    const float* Wqkv_f = (const float*)d_in[1];  // [2048][3072]
    const float* Wff_f  = (const float*)d_in[2];  // [1024][1024]
    const float* bff    = (const float*)d_in[3];  // [1024]
    float* out = (float*)d_out;                   // [BS][1024]

    // batched attention (z=4) needs 4x probs; fall back if ws too small
    const size_t need4 = 67108864UL + 12582912UL + 2097152UL + 100663296UL +
                         33554432UL + 4UL * 33554432UL + 33554432UL + 65536UL +
                         4UL * 16 * 4096 * 4;
    const bool batched = ws_size >= need4;
    const int Z = batched ? 4 : 1;

    char* p = (char*)d_ws;
    u16* x_bf  = (u16*)p; p += BS * 2048 * 2;
    u16* WqkvT = (u16*)p; p += 3072L * 2048 * 2;
    u16* WffT  = (u16*)p; p += 1024L * 1024 * 2;
    u16* kqv   = (u16*)p; p += BS * 3072 * 2;
    u16* vT    = (u16*)p; p += 4L * 1024 * 4096 * 2;
    u16* probs = (u16*)p; p += (long)Z * 4096L * 4096 * 2;
    u16* attn  = (u16*)p; p += BS * 1024 * 2;
    float* rrow = (float*)p; p += 4L * 4096 * 4;   // always full [4][4096]
    float* psum = (float*)p; p += (long)Z * 16 * 4096 * 4;

    // 1. conversions / weight transposes
    k_cvt_f32_bf16<<<dim3((unsigned)(BS * 2048 / 2048)), 256, 0, stream>>>(x_f, x_bf, BS * 2048);
    k_transpose_bf16<float><<<dim3(3072 / 32, 2048 / 32, 1), dim3(32, 8), 0, stream>>>(
        Wqkv_f, 3072, 0, WqkvT, 2048, 0, 2048, 3072);
    k_transpose_bf16<float><<<dim3(1024 / 32, 1024 / 32, 1), dim3(32, 8), 0, stream>>>(
        Wff_f, 1024, 0, WffT, 1024, 0, 1024, 1024);

    // 2. kqv = X @ W_qkv [16384 x 3072], K=2048 (nwg = 12*128 = 1536)
    //    V-columns (bx>=8) are written TRANSPOSED directly to vT (EPI 4).
    k_gemm3b<4><<<dim3(12 * 128, 1, 1), 512, 0, stream>>>(
        x_bf, 2048, 0, WqkvT, 2048, 0, kqv, 3072, 0, 2048, 0.f, nullptr, 0,
        nullptr, nullptr, 12, vT);

    // 3. attention: probs = exp(Q K^T * scale) with fused row-sum partials;
    //    O_unnorm = probs @ V (normalization deferred to the ff epilogue)
    const float scale = 0.08838834764831845f;  // 1/sqrt(128)
    for (int b = 0; b < 4; b += Z) {
        const u16* kbase = kqv + (long)b * S * 3072;  // k at +0, q at +1024
        k_gemm3b<1><<<dim3(16 * 32, 1, Z), 512, 0, stream>>>(
            kbase + 1024, 3072, (long)S * 3072, kbase, 3072, (long)S * 3072,
            probs, 4096, (long)S * S, 1024, scale, nullptr, 0, nullptr, psum, 16,
            nullptr);
        k_psum_recip<<<(Z * 4096 + 255) / 256, 256, 0, stream>>>(
            psum, rrow + (long)b * 4096, 16, (long)Z * 4096);
        k_gemm3b<0><<<dim3(4 * 32, 1, Z), 512, 0, stream>>>(
            probs, 4096, (long)S * S, vT + (long)b * 1024 * 4096, 4096, 1024L * 4096,
            attn + (long)b * S * 1024, 1024, (long)S * 1024,
            4096, 0.f, nullptr, 0, nullptr, nullptr, 4, nullptr);
    }

    // 4. out = rrow[row] * (attn_unnorm @ W_ff) + b_ff  (fp32, nwg = 512)
    k_gemm3b<3><<<dim3(4 * 128, 1, 1), 512, 0, stream>>>(
        attn, 1024, 0, WffT, 1024, 0, out, 1024, 0, 1024, 0.f, rrow, 0,
        bff, nullptr, 4, nullptr);
}

// Round 23
// 596.614 us; speedup vs baseline: 1.2634x; 1.0110x over previous
//
#include <hip/hip_runtime.h>

typedef unsigned short u16;
using bf16x8 = __attribute__((ext_vector_type(8))) __bf16;
using f32x4  = __attribute__((ext_vector_type(4))) float;
using u16x8  = __attribute__((ext_vector_type(8))) u16;

__device__ __forceinline__ u16 f2bf(float f) {
    unsigned u = __builtin_bit_cast(unsigned, f);
    u += 0x7FFFu + ((u >> 16) & 1u);           // round-to-nearest-even
    return (u16)(u >> 16);
}
__device__ __forceinline__ float bf2f(u16 h) {
    unsigned u = ((unsigned)h) << 16;
    return __builtin_bit_cast(float, u);
}
__device__ __forceinline__ u16 to_bf(float f) { return f2bf(f); }
__device__ __forceinline__ u16 to_bf(u16 h)   { return h; }

// async global->LDS, 16B per lane; LDS base must be wave-uniform.
__device__ __forceinline__ void gload_lds16(const u16* g, u16* l) {
    __builtin_amdgcn_global_load_lds(
        (const __attribute__((address_space(1))) unsigned int*)g,
        (__attribute__((address_space(3))) unsigned int*)l,
        16, 0, 0);
}

// ---------------- fp32 -> bf16 elementwise (vectorized) ----------------
__global__ __launch_bounds__(256) void k_cvt_f32_bf16(const float* __restrict__ in,
                                                      u16* __restrict__ out, long n) {
    long i = ((long)blockIdx.x * 256 + threadIdx.x) * 8;
    if (i + 8 > n) return;
    f32x4 a = *(const f32x4*)(in + i);
    f32x4 b = *(const f32x4*)(in + i + 4);
    u16x8 o;
    o[0] = f2bf(a[0]); o[1] = f2bf(a[1]); o[2] = f2bf(a[2]); o[3] = f2bf(a[3]);
    o[4] = f2bf(b[0]); o[5] = f2bf(b[1]); o[6] = f2bf(b[2]); o[7] = f2bf(b[3]);
    *(u16x8*)(out + i) = o;
}

// ---------------- tiled transpose (f32->bf16) for weights ----------------
template <typename T>
__global__ __launch_bounds__(256) void k_transpose_bf16(
    const T* __restrict__ in, long in_rs, long in_bs,
    u16* __restrict__ out, long out_rs, long out_bs, int R, int C) {
    __shared__ u16 tile[32][33];
    const int b = blockIdx.z;
    const T* ip = in + (long)b * in_bs;
    u16* op = out + (long)b * out_bs;
    const int tx = threadIdx.x, ty = threadIdx.y;
    const long r0 = (long)blockIdx.y * 32, c0 = (long)blockIdx.x * 32;
#pragma unroll
    for (int i = 0; i < 4; ++i) {
        int r = ty + i * 8;
        tile[r][tx] = to_bf(ip[(r0 + r) * in_rs + c0 + tx]);
    }
    __syncthreads();
#pragma unroll
    for (int i = 0; i < 4; ++i) {
        int c = ty + i * 8;
        op[(c0 + c) * out_rs + r0 + tx] = tile[tx][c];
    }
}

// --------- reduce per-block partial row sums -> reciprocal ----------
// psum: [Z][nx][4096] (written by QK^T blocks), rrow: [Z*4096]
__global__ __launch_bounds__(256) void k_psum_recip(const float* __restrict__ psum,
                                                    float* __restrict__ rrow,
                                                    int nx, long total) {
    long idx = (long)blockIdx.x * 256 + threadIdx.x;
    if (idx >= total) return;
    const long z = idx >> 12, row = idx & 4095;
    const float* p = psum + (z * nx) * 4096 + row;
    float s = 0.f;
    for (int x = 0; x < nx; ++x) s += p[(long)x * 4096];
    rrow[idx] = 1.0f / s;
}

// ====== 128x256 bf16 GEMM, BK=32, 3-buffer ring, 2 blocks/CU, C = A*B^T ======
// Round-22 proven structure (603.2 us): T1 XCD-chunked block swizzle, 8 waves
// (2M x 4N), per-wave 64x64, LDS swizzle byte ^= ((byte>>9)&1)<<5 both sides,
// per tile: 8 ds_read_b128 + stage t+2 + 16 MFMA -> VMC(3) -> barrier.
// Plain stores (r21: scalar nt stores amplify writes ~2.7x). rrow-commute:
// PV writes unnormalized O (EPI 0); ff applies rrow[row]*acc + bias.
// EPI 0: bf16(acc)  1: bf16(exp(acc*scale)) + fused row-sum partials
// EPI 3: f32(rrow[row]*acc + bias[col])
// EPI 4 (kqv): DENSE k/q split — bx<4 -> kmat[rg][cg], bx in [4,8) ->
//   qmat[rg][cg-1024] (lda 1024 each: QK^T panels pack L2 lines densely);
//   bx>=8 -> tile TRANSPOSED to vT via dead staging LDS retile
//   ([256 col][136-pad row]); bit-identical values everywhere.

#define VMC(n) asm volatile("s_waitcnt vmcnt(" #n ")" ::: "memory")
#define SCHB   __builtin_amdgcn_sched_barrier(0)
#define BAR    __builtin_amdgcn_s_barrier()
#define PRIO1  __builtin_amdgcn_s_setprio(1)
#define PRIO0  __builtin_amdgcn_s_setprio(0)
#define SWZ(b) ((b) ^ ((((b) >> 9) & 1) << 5))

template <int EPI>
__global__ __launch_bounds__(512, 4) void k_gemm3b(
    const u16* __restrict__ Ag, long lda, long sA,
    const u16* __restrict__ Bg, long ldb, long sB,
    void* __restrict__ Cv, long ldc, long sC,
    int K, float scale, const float* __restrict__ rrowZ, long sR,
    const float* __restrict__ bias, float* __restrict__ psum, int nx,
    u16* __restrict__ vTp, u16* __restrict__ qmp) {
    __shared__ __align__(16) u16 LDSbuf[3 * 128 * 32 + 3 * 256 * 32];
    u16 (*As)[128 * 32] = (u16(*)[128 * 32])LDSbuf;
    u16 (*Bs)[256 * 32] = (u16(*)[256 * 32])(LDSbuf + 3 * 128 * 32);

    const int tid = threadIdx.x;
    const int lane = tid & 63, wid = tid >> 6;
    const int wm = wid >> 2, wn = wid & 3;   // 2(M) x 4(N) wave grid
    const int z = blockIdx.z;
    // XCD-chunked bijective swizzle (nwg % 8 == 0 for all our launches)
    const int nwg = gridDim.x;
    const int bid = blockIdx.x;
    const int swzb = (bid & 7) * (nwg >> 3) + (bid >> 3);
    const int bx = swzb % nx, by = swzb / nx;
    const long m0 = (long)by * 128;
    const long n0 = (long)bx * 256;
    const u16* A = Ag + (long)z * sA;
    const u16* B = Bg + (long)z * sB;

    // staging sources (linear LDS dest; pre-swizzled global src).
    long aSrc, bSrc0, bSrc1;
    {
        int dg = SWZ(tid * 16);
        aSrc = (m0 + (dg >> 6)) * lda + ((dg & 63) >> 1);
        bSrc0 = (n0 + (dg >> 6)) * ldb + ((dg & 63) >> 1);
        dg = SWZ(8192 + tid * 16);
        bSrc1 = (n0 + (dg >> 6)) * ldb + ((dg & 63) >> 1);
    }
    const int r16 = lane & 15, g = lane >> 4;
    const int vA = SWZ((wm * 64 + r16) * 64 + g * 16);   // byte off in A buf
    const int vB = SWZ((wn * 64 + r16) * 64 + g * 16);   // byte off in B buf

#define STG(bb, kt) do { \
        gload_lds16(A + aSrc + (kt), &As[bb][wid * 512]); \
        gload_lds16(B + bSrc0 + (kt), &Bs[bb][wid * 512]); \
        gload_lds16(B + bSrc1 + (kt), &Bs[bb][4096 + wid * 512]); } while (0)
#define LD4_A(bb) do { _Pragma("unroll") for (int _i = 0; _i < 4; ++_i) \
        afr[_i] = *(const bf16x8*)((const char*)&As[bb][0] + vA + _i * 1024); } while (0)
#define LD4_B(bb) do { _Pragma("unroll") for (int _i = 0; _i < 4; ++_i) \
        bfr[_i] = *(const bf16x8*)((const char*)&Bs[bb][0] + vB + _i * 1024); } while (0)
#define MM16() do { \
        _Pragma("unroll") for (int mf = 0; mf < 4; ++mf) \
        _Pragma("unroll") for (int nf = 0; nf < 4; ++nf) \
            acc[mf][nf] = __builtin_amdgcn_mfma_f32_16x16x32_bf16( \
                afr[mf], bfr[nf], acc[mf][nf], 0, 0, 0); } while (0)

    f32x4 acc[4][4] = {};
    bf16x8 afr[4], bfr[4];

    const int NT = K >> 5;   // K-tiles of 32; NT >= 3 assumed
    // prologue: stage tiles 0 and 1
    STG(0, 0); STG(1, 32);
    VMC(3); SCHB;            // tile 0's 3 loads landed (own); BAR -> collective
    BAR; SCHB;

    int b0 = 0, b1 = 1, b2 = 2;
    for (int t = 0; t < NT; ++t) {
        LD4_A(b0); LD4_B(b0);                       // 8 ds_read_b128
        if (t + 2 < NT) STG(b2, (long)(t + 2) * 32);
        PRIO1; MM16(); PRIO0;                       // compiler-counted lgkmcnt
        if (t + 2 < NT) { VMC(3); }                 // retire tile t+1's loads
        else if (t + 1 < NT) { VMC(0); }            // tail drain
        BAR; SCHB;
        int tm = b0; b0 = b1; b1 = b2; b2 = tm;
    }

    // epilogue. C/D layout: col = lane&15, row = (lane>>4)*4 + j
    const int r_in = (lane >> 4) * 4;
    const int c_in = lane & 15;

    if constexpr (EPI == 4) {
        if (bx >= 8) {
            // transposed V write: acc -> LDS [256 col][136-pad row] -> vT
            u16* t = LDSbuf;
#pragma unroll
            for (int mf = 0; mf < 4; ++mf) {
#pragma unroll
                for (int nf = 0; nf < 4; ++nf) {
                    const int c = wn * 64 + nf * 16 + c_in;
                    const int r = wm * 64 + mf * 16 + r_in;
                    ushort4 pk;
                    pk.x = f2bf(acc[mf][nf][0]); pk.y = f2bf(acc[mf][nf][1]);
                    pk.z = f2bf(acc[mf][nf][2]); pk.w = f2bf(acc[mf][nf][3]);
                    *(ushort4*)(t + c * 136 + r) = pk;
                }
            }
            __syncthreads();
            const int cc = tid >> 1, hf = tid & 1;
            const long zz = m0 >> 12;              // batch of this row panel
            u16* dst = vTp + zz * (1024L * 4096) +
                       (n0 - 2048 + cc) * 4096L + (m0 & 4095) + hf * 64;
            const u16* src = t + cc * 136 + hf * 64;
#pragma unroll
            for (int i = 0; i < 8; ++i)
                *(u16x8*)(dst + i * 8) = *(const u16x8*)(src + i * 8);
            return;
        }
        // bx<4 -> kmat (Cv), bx in [4,8) -> qmat; both dense lda=1024
        u16* dmat = (bx < 4) ? (u16*)Cv : qmp;
#pragma unroll
        for (int mf = 0; mf < 4; ++mf) {
#pragma unroll
            for (int nf = 0; nf < 4; ++nf) {
                const long cg = (n0 + wn * 64 + nf * 16 + c_in) & 1023;
#pragma unroll
                for (int j = 0; j < 4; ++j) {
                    const long rg = m0 + wm * 64 + mf * 16 + r_in + j;
                    dmat[rg * 1024 + cg] = f2bf(acc[mf][nf][j]);
                }
            }
        }
        return;
    }

    float rsum[4][4];
    if constexpr (EPI == 1) {
#pragma unroll
        for (int a = 0; a < 4; ++a)
#pragma unroll
            for (int b = 0; b < 4; ++b) rsum[a][b] = 0.f;
    }
#pragma unroll
    for (int mf = 0; mf < 4; ++mf) {
#pragma unroll
        for (int nf = 0; nf < 4; ++nf) {
            const long cg = n0 + wn * 64 + nf * 16 + c_in;
#pragma unroll
            for (int j = 0; j < 4; ++j) {
                const long rg = m0 + wm * 64 + mf * 16 + r_in + j;
                float v = acc[mf][nf][j];
                if constexpr (EPI == 0) {
                    ((u16*)Cv)[(long)z * sC + rg * ldc + cg] = f2bf(v);
                } else if constexpr (EPI == 1) {
                    float e = __expf(v * scale);
                    ((u16*)Cv)[(long)z * sC + rg * ldc + cg] = f2bf(e);
                    rsum[mf][j] += e;
                } else {  // EPI == 3: out = rrow[row]*acc + bias[col]
                    ((float*)Cv)[(long)z * sC + rg * ldc + cg] =
                        rrowZ[rg] * v + bias[cg];
                }
            }
        }
    }
    if constexpr (EPI == 1) {
        // per-block partial row sums -> psum[(z*nx + bx)*M + m0 + row]
        float* ps = (float*)LDSbuf;      // [128][4] scratch (staging LDS dead)
#pragma unroll
        for (int mf = 0; mf < 4; ++mf) {
#pragma unroll
            for (int j = 0; j < 4; ++j) {
                float s = rsum[mf][j];
#pragma unroll
                for (int w = 1; w < 16; w <<= 1) s += __shfl_xor(s, w);
                if ((lane & 15) == 0)
                    ps[(wm * 64 + mf * 16 + (lane >> 4) * 4 + j) * 4 + wn] = s;
            }
        }
        __syncthreads();
        if (tid < 128) {
            float s = ps[tid * 4] + ps[tid * 4 + 1] + ps[tid * 4 + 2] + ps[tid * 4 + 3];
            const long M = (long)(nwg / nx) * 128;
            psum[((long)z * nx + bx) * M + m0 + tid] = s;
        }
    }
#undef MM16
#undef LD4_A
#undef LD4_B
#undef STG
}

extern "C" void kernel_launch(void* const* d_in, const int* in_sizes, int n_in,
                              void* d_out, int out_size, void* d_ws, size_t ws_size,
                              hipStream_t stream) {
    (void)in_sizes; (void)n_in; (void)out_size;
    const int S = 4096;
    const long BS = 4L * S;  // 16384 tokens
    const float* x_f    = (const float*)d_in[0];  // [BS][2048]
    const float* Wqkv_f = (const float*)d_in[1];  // [2048][3072]
    const float* Wff_f  = (const float*)d_in[2];  // [1024][1024]
    const float* bff    = (const float*)d_in[3];  // [1024]
    float* out = (float*)d_out;                   // [BS][1024]

    // batched attention (z=4) needs 4x probs; fall back if ws too small
    const size_t need4 = 67108864UL + 12582912UL + 2097152UL + 2UL * 33554432UL +
                         33554432UL + 4UL * 33554432UL + 33554432UL + 65536UL +
                         4UL * 16 * 4096 * 4;
    const bool batched = ws_size >= need4;
    const int Z = batched ? 4 : 1;

    char* p = (char*)d_ws;
    u16* x_bf  = (u16*)p; p += BS * 2048 * 2;
    u16* WqkvT = (u16*)p; p += 3072L * 2048 * 2;
    u16* WffT  = (u16*)p; p += 1024L * 1024 * 2;
    u16* kmat  = (u16*)p; p += BS * 1024 * 2;      // dense K  [BS][1024]
    u16* qmat  = (u16*)p; p += BS * 1024 * 2;      // dense Q  [BS][1024]
    u16* vT    = (u16*)p; p += 4L * 1024 * 4096 * 2;
    u16* probs = (u16*)p; p += (long)Z * 4096L * 4096 * 2;
    u16* attn  = (u16*)p; p += BS * 1024 * 2;
    float* rrow = (float*)p; p += 4L * 4096 * 4;   // always full [4][4096]
    float* psum = (float*)p; p += (long)Z * 16 * 4096 * 4;

    // 1. conversions / weight transposes
    k_cvt_f32_bf16<<<dim3((unsigned)(BS * 2048 / 2048)), 256, 0, stream>>>(x_f, x_bf, BS * 2048);
    k_transpose_bf16<float><<<dim3(3072 / 32, 2048 / 32, 1), dim3(32, 8), 0, stream>>>(
        Wqkv_f, 3072, 0, WqkvT, 2048, 0, 2048, 3072);
    k_transpose_bf16<float><<<dim3(1024 / 32, 1024 / 32, 1), dim3(32, 8), 0, stream>>>(
        Wff_f, 1024, 0, WffT, 1024, 0, 1024, 1024);

    // 2. kqv = X @ W_qkv [16384 x 3072], K=2048 (nwg = 12*128 = 1536)
    //    k -> kmat (dense), q -> qmat (dense), v -> vT (transposed), EPI 4.
    k_gemm3b<4><<<dim3(12 * 128, 1, 1), 512, 0, stream>>>(
        x_bf, 2048, 0, WqkvT, 2048, 0, kmat, 1024, 0, 2048, 0.f, nullptr, 0,
        nullptr, nullptr, 12, vT, qmat);

    // 3. attention: probs = exp(Q K^T * scale) with fused row-sum partials;
    //    O_unnorm = probs @ V (normalization deferred to the ff epilogue)
    const float scale = 0.08838834764831845f;  // 1/sqrt(128)
    for (int b = 0; b < 4; b += Z) {
        k_gemm3b<1><<<dim3(16 * 32, 1, Z), 512, 0, stream>>>(
            qmat + (long)b * S * 1024, 1024, (long)S * 1024,
            kmat + (long)b * S * 1024, 1024, (long)S * 1024,
            probs, 4096, (long)S * S, 1024, scale, nullptr, 0, nullptr, psum, 16,
            nullptr, nullptr);
        k_psum_recip<<<(Z * 4096 + 255) / 256, 256, 0, stream>>>(
            psum, rrow + (long)b * 4096, 16, (long)Z * 4096);
        k_gemm3b<0><<<dim3(4 * 32, 1, Z), 512, 0, stream>>>(
            probs, 4096, (long)S * S, vT + (long)b * 1024 * 4096, 4096, 1024L * 4096,
            attn + (long)b * S * 1024, 1024, (long)S * 1024,
            4096, 0.f, nullptr, 0, nullptr, nullptr, 4, nullptr, nullptr);
    }

    // 4. out = rrow[row] * (attn_unnorm @ W_ff) + b_ff  (fp32, nwg = 512)
    k_gemm3b<3><<<dim3(4 * 128, 1, 1), 512, 0, stream>>>(
        attn, 1024, 0, WffT, 1024, 0, out, 1024, 0, 1024, 0.f, rrow, 0,
        bff, nullptr, 4, nullptr, nullptr);
}

// Round 24
// 596.155 us; speedup vs baseline: 1.2643x; 1.0008x over previous
//
#include <hip/hip_runtime.h>

typedef unsigned short u16;
using bf16x8 = __attribute__((ext_vector_type(8))) __bf16;
using f32x4  = __attribute__((ext_vector_type(4))) float;
using u16x8  = __attribute__((ext_vector_type(8))) u16;

__device__ __forceinline__ u16 f2bf(float f) {
    unsigned u = __builtin_bit_cast(unsigned, f);
    u += 0x7FFFu + ((u >> 16) & 1u);           // round-to-nearest-even
    return (u16)(u >> 16);
}
__device__ __forceinline__ float bf2f(u16 h) {
    unsigned u = ((unsigned)h) << 16;
    return __builtin_bit_cast(float, u);
}
__device__ __forceinline__ u16 to_bf(float f) { return f2bf(f); }
__device__ __forceinline__ u16 to_bf(u16 h)   { return h; }

// async global->LDS, 16B per lane; LDS base must be wave-uniform.
__device__ __forceinline__ void gload_lds16(const u16* g, u16* l) {
    __builtin_amdgcn_global_load_lds(
        (const __attribute__((address_space(1))) unsigned int*)g,
        (__attribute__((address_space(3))) unsigned int*)l,
        16, 0, 0);
}

// ------- fp32 -> bf16 elementwise (vectorized, grid-stride, G11) -------
__global__ __launch_bounds__(256) void k_cvt_f32_bf16(const float* __restrict__ in,
                                                      u16* __restrict__ out, long n) {
    const long stride = (long)gridDim.x * 256 * 8;
    for (long i = ((long)blockIdx.x * 256 + threadIdx.x) * 8; i + 8 <= n; i += stride) {
        f32x4 a = *(const f32x4*)(in + i);
        f32x4 b = *(const f32x4*)(in + i + 4);
        u16x8 o;
        o[0] = f2bf(a[0]); o[1] = f2bf(a[1]); o[2] = f2bf(a[2]); o[3] = f2bf(a[3]);
        o[4] = f2bf(b[0]); o[5] = f2bf(b[1]); o[6] = f2bf(b[2]); o[7] = f2bf(b[3]);
        *(u16x8*)(out + i) = o;
    }
}

// ---------------- tiled transpose (f32->bf16) for weights ----------------
template <typename T>
__global__ __launch_bounds__(256) void k_transpose_bf16(
    const T* __restrict__ in, long in_rs, long in_bs,
    u16* __restrict__ out, long out_rs, long out_bs, int R, int C) {
    __shared__ u16 tile[32][33];
    const int b = blockIdx.z;
    const T* ip = in + (long)b * in_bs;
    u16* op = out + (long)b * out_bs;
    const int tx = threadIdx.x, ty = threadIdx.y;
    const long r0 = (long)blockIdx.y * 32, c0 = (long)blockIdx.x * 32;
#pragma unroll
    for (int i = 0; i < 4; ++i) {
        int r = ty + i * 8;
        tile[r][tx] = to_bf(ip[(r0 + r) * in_rs + c0 + tx]);
    }
    __syncthreads();
#pragma unroll
    for (int i = 0; i < 4; ++i) {
        int c = ty + i * 8;
        op[(c0 + c) * out_rs + r0 + tx] = tile[tx][c];
    }
}

// --------- reduce per-block partial row sums -> reciprocal ----------
// psum: [Z][nx][4096] (written by QK^T blocks), rrow: [Z*4096]
__global__ __launch_bounds__(256) void k_psum_recip(const float* __restrict__ psum,
                                                    float* __restrict__ rrow,
                                                    int nx, long total) {
    long idx = (long)blockIdx.x * 256 + threadIdx.x;
    if (idx >= total) return;
    const long z = idx >> 12, row = idx & 4095;
    const float* p = psum + (z * nx) * 4096 + row;
    float s = 0.f;
    for (int x = 0; x < nx; ++x) s += p[(long)x * 4096];
    rrow[idx] = 1.0f / s;
}

// ====== 128x256 bf16 GEMM, BK=32, 3-buffer ring, 2 blocks/CU, C = A*B^T ======
// Round-23 proven structure (596.6 us): T1 XCD-chunked block swizzle, 8 waves
// (2M x 4N), per-wave 64x64, LDS swizzle byte ^= ((byte>>9)&1)<<5 both sides,
// per tile: 8 ds_read_b128 + stage t+2 + 16 MFMA -> VMC(3) -> barrier.
// Plain stores (r21: scalar nt stores amplify writes ~2.7x). rrow-commute:
// PV writes unnormalized O (EPI 0); ff applies rrow[row]*acc + bias.
// EPI 0: bf16(acc)  1: bf16(exp(acc*scale)) + fused row-sum partials
// EPI 3: f32(rrow[row]*acc + bias[col])
// EPI 4 (kqv): DENSE k/q split — bx<4 -> kmat[rg][cg], bx in [4,8) ->
//   qmat[rg][cg-1024] (lda 1024 each); bx>=8 -> tile TRANSPOSED to vT via
//   dead staging LDS retile ([256 col][136-pad row]); bit-identical values.

#define VMC(n) asm volatile("s_waitcnt vmcnt(" #n ")" ::: "memory")
#define SCHB   __builtin_amdgcn_sched_barrier(0)
#define BAR    __builtin_amdgcn_s_barrier()
#define PRIO1  __builtin_amdgcn_s_setprio(1)
#define PRIO0  __builtin_amdgcn_s_setprio(0)
#define SWZ(b) ((b) ^ ((((b) >> 9) & 1) << 5))

template <int EPI>
__global__ __launch_bounds__(512, 4) void k_gemm3b(
    const u16* __restrict__ Ag, long lda, long sA,
    const u16* __restrict__ Bg, long ldb, long sB,
    void* __restrict__ Cv, long ldc, long sC,
    int K, float scale, const float* __restrict__ rrowZ, long sR,
    const float* __restrict__ bias, float* __restrict__ psum, int nx,
    u16* __restrict__ vTp, u16* __restrict__ qmp) {
    __shared__ __align__(16) u16 LDSbuf[3 * 128 * 32 + 3 * 256 * 32];
    u16 (*As)[128 * 32] = (u16(*)[128 * 32])LDSbuf;
    u16 (*Bs)[256 * 32] = (u16(*)[256 * 32])(LDSbuf + 3 * 128 * 32);

    const int tid = threadIdx.x;
    const int lane = tid & 63, wid = tid >> 6;
    const int wm = wid >> 2, wn = wid & 3;   // 2(M) x 4(N) wave grid
    const int z = blockIdx.z;
    // XCD-chunked bijective swizzle (nwg % 8 == 0 for all our launches)
    const int nwg = gridDim.x;
    const int bid = blockIdx.x;
    const int swzb = (bid & 7) * (nwg >> 3) + (bid >> 3);
    const int bx = swzb % nx, by = swzb / nx;
    const long m0 = (long)by * 128;
    const long n0 = (long)bx * 256;
    const u16* A = Ag + (long)z * sA;
    const u16* B = Bg + (long)z * sB;

    // staging sources (linear LDS dest; pre-swizzled global src).
    long aSrc, bSrc0, bSrc1;
    {
        int dg = SWZ(tid * 16);
        aSrc = (m0 + (dg >> 6)) * lda + ((dg & 63) >> 1);
        bSrc0 = (n0 + (dg >> 6)) * ldb + ((dg & 63) >> 1);
        dg = SWZ(8192 + tid * 16);
        bSrc1 = (n0 + (dg >> 6)) * ldb + ((dg & 63) >> 1);
    }
    const int r16 = lane & 15, g = lane >> 4;
    const int vA = SWZ((wm * 64 + r16) * 64 + g * 16);   // byte off in A buf
    const int vB = SWZ((wn * 64 + r16) * 64 + g * 16);   // byte off in B buf

#define STG(bb, kt) do { \
        gload_lds16(A + aSrc + (kt), &As[bb][wid * 512]); \
        gload_lds16(B + bSrc0 + (kt), &Bs[bb][wid * 512]); \
        gload_lds16(B + bSrc1 + (kt), &Bs[bb][4096 + wid * 512]); } while (0)
#define LD4_A(bb) do { _Pragma("unroll") for (int _i = 0; _i < 4; ++_i) \
        afr[_i] = *(const bf16x8*)((const char*)&As[bb][0] + vA + _i * 1024); } while (0)
#define LD4_B(bb) do { _Pragma("unroll") for (int _i = 0; _i < 4; ++_i) \
        bfr[_i] = *(const bf16x8*)((const char*)&Bs[bb][0] + vB + _i * 1024); } while (0)
#define MM16() do { \
        _Pragma("unroll") for (int mf = 0; mf < 4; ++mf) \
        _Pragma("unroll") for (int nf = 0; nf < 4; ++nf) \
            acc[mf][nf] = __builtin_amdgcn_mfma_f32_16x16x32_bf16( \
                afr[mf], bfr[nf], acc[mf][nf], 0, 0, 0); } while (0)

    f32x4 acc[4][4] = {};
    bf16x8 afr[4], bfr[4];

    const int NT = K >> 5;   // K-tiles of 32; NT >= 3 assumed
    // prologue: stage tiles 0 and 1
    STG(0, 0); STG(1, 32);
    VMC(3); SCHB;            // tile 0's 3 loads landed (own); BAR -> collective
    BAR; SCHB;

    int b0 = 0, b1 = 1, b2 = 2;
    for (int t = 0; t < NT; ++t) {
        LD4_A(b0); LD4_B(b0);                       // 8 ds_read_b128
        if (t + 2 < NT) STG(b2, (long)(t + 2) * 32);
        PRIO1; MM16(); PRIO0;                       // compiler-counted lgkmcnt
        if (t + 2 < NT) { VMC(3); }                 // retire tile t+1's loads
        else if (t + 1 < NT) { VMC(0); }            // tail drain
        BAR; SCHB;
        int tm = b0; b0 = b1; b1 = b2; b2 = tm;
    }

    // epilogue. C/D layout: col = lane&15, row = (lane>>4)*4 + j
    const int r_in = (lane >> 4) * 4;
    const int c_in = lane & 15;

    if constexpr (EPI == 4) {
        if (bx >= 8) {
            // transposed V write: acc -> LDS [256 col][136-pad row] -> vT
            u16* t = LDSbuf;
#pragma unroll
            for (int mf = 0; mf < 4; ++mf) {
#pragma unroll
                for (int nf = 0; nf < 4; ++nf) {
                    const int c = wn * 64 + nf * 16 + c_in;
                    const int r = wm * 64 + mf * 16 + r_in;
                    ushort4 pk;
                    pk.x = f2bf(acc[mf][nf][0]); pk.y = f2bf(acc[mf][nf][1]);
                    pk.z = f2bf(acc[mf][nf][2]); pk.w = f2bf(acc[mf][nf][3]);
                    *(ushort4*)(t + c * 136 + r) = pk;
                }
            }
            __syncthreads();
            const int cc = tid >> 1, hf = tid & 1;
            const long zz = m0 >> 12;              // batch of this row panel
            u16* dst = vTp + zz * (1024L * 4096) +
                       (n0 - 2048 + cc) * 4096L + (m0 & 4095) + hf * 64;
            const u16* src = t + cc * 136 + hf * 64;
#pragma unroll
            for (int i = 0; i < 8; ++i)
                *(u16x8*)(dst + i * 8) = *(const u16x8*)(src + i * 8);
            return;
        }
        // bx<4 -> kmat (Cv), bx in [4,8) -> qmat; both dense lda=1024
        u16* dmat = (bx < 4) ? (u16*)Cv : qmp;
#pragma unroll
        for (int mf = 0; mf < 4; ++mf) {
#pragma unroll
            for (int nf = 0; nf < 4; ++nf) {
                const long cg = (n0 + wn * 64 + nf * 16 + c_in) & 1023;
#pragma unroll
                for (int j = 0; j < 4; ++j) {
                    const long rg = m0 + wm * 64 + mf * 16 + r_in + j;
                    dmat[rg * 1024 + cg] = f2bf(acc[mf][nf][j]);
                }
            }
        }
        return;
    }

    float rsum[4][4];
    if constexpr (EPI == 1) {
#pragma unroll
        for (int a = 0; a < 4; ++a)
#pragma unroll
            for (int b = 0; b < 4; ++b) rsum[a][b] = 0.f;
    }
#pragma unroll
    for (int mf = 0; mf < 4; ++mf) {
#pragma unroll
        for (int nf = 0; nf < 4; ++nf) {
            const long cg = n0 + wn * 64 + nf * 16 + c_in;
#pragma unroll
            for (int j = 0; j < 4; ++j) {
                const long rg = m0 + wm * 64 + mf * 16 + r_in + j;
                float v = acc[mf][nf][j];
                if constexpr (EPI == 0) {
                    ((u16*)Cv)[(long)z * sC + rg * ldc + cg] = f2bf(v);
                } else if constexpr (EPI == 1) {
                    float e = __expf(v * scale);
                    ((u16*)Cv)[(long)z * sC + rg * ldc + cg] = f2bf(e);
                    rsum[mf][j] += e;
                } else {  // EPI == 3: out = rrow[row]*acc + bias[col]
                    ((float*)Cv)[(long)z * sC + rg * ldc + cg] =
                        rrowZ[rg] * v + bias[cg];
                }
            }
        }
    }
    if constexpr (EPI == 1) {
        // per-block partial row sums -> psum[(z*nx + bx)*M + m0 + row]
        float* ps = (float*)LDSbuf;      // [128][4] scratch (staging LDS dead)
#pragma unroll
        for (int mf = 0; mf < 4; ++mf) {
#pragma unroll
            for (int j = 0; j < 4; ++j) {
                float s = rsum[mf][j];
#pragma unroll
                for (int w = 1; w < 16; w <<= 1) s += __shfl_xor(s, w);
                if ((lane & 15) == 0)
                    ps[(wm * 64 + mf * 16 + (lane >> 4) * 4 + j) * 4 + wn] = s;
            }
        }
        __syncthreads();
        if (tid < 128) {
            float s = ps[tid * 4] + ps[tid * 4 + 1] + ps[tid * 4 + 2] + ps[tid * 4 + 3];
            const long M = (long)(nwg / nx) * 128;
            psum[((long)z * nx + bx) * M + m0 + tid] = s;
        }
    }
#undef MM16
#undef LD4_A
#undef LD4_B
#undef STG
}

extern "C" void kernel_launch(void* const* d_in, const int* in_sizes, int n_in,
                              void* d_out, int out_size, void* d_ws, size_t ws_size,
                              hipStream_t stream) {
    (void)in_sizes; (void)n_in; (void)out_size;
    const int S = 4096;
    const long BS = 4L * S;  // 16384 tokens
    const float* x_f    = (const float*)d_in[0];  // [BS][2048]
    const float* Wqkv_f = (const float*)d_in[1];  // [2048][3072]
    const float* Wff_f  = (const float*)d_in[2];  // [1024][1024]
    const float* bff    = (const float*)d_in[3];  // [1024]
    float* out = (float*)d_out;                   // [BS][1024]

    // batched attention (z=4) needs 4x probs; fall back if ws too small
    const size_t need4 = 67108864UL + 12582912UL + 2097152UL + 2UL * 33554432UL +
                         33554432UL + 4UL * 33554432UL + 33554432UL + 65536UL +
                         4UL * 16 * 4096 * 4;
    const bool batched = ws_size >= need4;
    const int Z = batched ? 4 : 1;

    char* p = (char*)d_ws;
    u16* x_bf  = (u16*)p; p += BS * 2048 * 2;
    u16* WqkvT = (u16*)p; p += 3072L * 2048 * 2;
    u16* WffT  = (u16*)p; p += 1024L * 1024 * 2;
    u16* kmat  = (u16*)p; p += BS * 1024 * 2;      // dense K  [BS][1024]
    u16* qmat  = (u16*)p; p += BS * 1024 * 2;      // dense Q  [BS][1024]
    u16* vT    = (u16*)p; p += 4L * 1024 * 4096 * 2;
    u16* probs = (u16*)p; p += (long)Z * 4096L * 4096 * 2;
    u16* attn  = (u16*)p; p += BS * 1024 * 2;
    float* rrow = (float*)p; p += 4L * 4096 * 4;   // always full [4][4096]
    float* psum = (float*)p; p += (long)Z * 16 * 4096 * 4;

    // 1. conversions / weight transposes (cvt: 2048-block grid-stride, G11)
    k_cvt_f32_bf16<<<dim3(2048), 256, 0, stream>>>(x_f, x_bf, BS * 2048);
    k_transpose_bf16<float><<<dim3(3072 / 32, 2048 / 32, 1), dim3(32, 8), 0, stream>>>(
        Wqkv_f, 3072, 0, WqkvT, 2048, 0, 2048, 3072);
    k_transpose_bf16<float><<<dim3(1024 / 32, 1024 / 32, 1), dim3(32, 8), 0, stream>>>(
        Wff_f, 1024, 0, WffT, 1024, 0, 1024, 1024);

    // 2. kqv = X @ W_qkv [16384 x 3072], K=2048 (nwg = 12*128 = 1536)
    //    k -> kmat (dense), q -> qmat (dense), v -> vT (transposed), EPI 4.
    k_gemm3b<4><<<dim3(12 * 128, 1, 1), 512, 0, stream>>>(
        x_bf, 2048, 0, WqkvT, 2048, 0, kmat, 1024, 0, 2048, 0.f, nullptr, 0,
        nullptr, nullptr, 12, vT, qmat);

    // 3. attention: probs = exp(Q K^T * scale) with fused row-sum partials;
    //    O_unnorm = probs @ V (normalization deferred to the ff epilogue)
    const float scale = 0.08838834764831845f;  // 1/sqrt(128)
    for (int b = 0; b < 4; b += Z) {
        k_gemm3b<1><<<dim3(16 * 32, 1, Z), 512, 0, stream>>>(
            qmat + (long)b * S * 1024, 1024, (long)S * 1024,
            kmat + (long)b * S * 1024, 1024, (long)S * 1024,
            probs, 4096, (long)S * S, 1024, scale, nullptr, 0, nullptr, psum, 16,
            nullptr, nullptr);
        k_psum_recip<<<(Z * 4096 + 255) / 256, 256, 0, stream>>>(
            psum, rrow + (long)b * 4096, 16, (long)Z * 4096);
        k_gemm3b<0><<<dim3(4 * 32, 1, Z), 512, 0, stream>>>(
            probs, 4096, (long)S * S, vT + (long)b * 1024 * 4096, 4096, 1024L * 4096,
            attn + (long)b * S * 1024, 1024, (long)S * 1024,
            4096, 0.f, nullptr, 0, nullptr, nullptr, 4, nullptr, nullptr);
    }

    // 4. out = rrow[row] * (attn_unnorm @ W_ff) + b_ff  (fp32, nwg = 512)
    k_gemm3b<3><<<dim3(4 * 128, 1, 1), 512, 0, stream>>>(
        attn, 1024, 0, WffT, 1024, 0, out, 1024, 0, 1024, 0.f, rrow, 0,
        bff, nullptr, 4, nullptr, nullptr);
}